// Round 2
// baseline (239.236 us; speedup 1.0000x reference)
//
#include <hip/hip_runtime.h>

#define IMG_W 1024
#define IMG_H 1024
#define BATCH 32
#define ROWS 16   // output rows per block, rolling 3-row register window

typedef float vfloat4 __attribute__((ext_vector_type(4)));

// Load input row ry, cols c0-1 .. c0+4, into R[0..5].
// Interior halo columns come from neighbor lanes via shuffle (the data is
// already in their vfloat4); only lanes 0/63 of each wave touch memory for
// the halo (cross-wave boundary), and those addresses are bounds-guarded.
__device__ __forceinline__ void load_row(const float* __restrict__ img,
                                         int ry, int c0, int lane,
                                         float (&R)[6])
{
    if (ry < 0 || ry >= IMG_H) {
#pragma unroll
        for (int k = 0; k < 6; ++k) R[k] = 0.f;
        return;
    }
    const float* p = img + (size_t)ry * IMG_W + c0;
    const vfloat4 v = *(const vfloat4*)p;
    float left  = __shfl_up(v.w, 1);    // lane-1's col c0-1
    float right = __shfl_down(v.x, 1);  // lane+1's col c0+4
    if (lane == 0)  left  = (c0 > 0)         ? p[-1] : 0.f;  // wave boundary
    if (lane == 63) right = (c0 + 4 < IMG_W) ? p[4]  : 0.f;  // wave boundary
    R[0] = left; R[1] = v.x; R[2] = v.y; R[3] = v.z; R[4] = v.w; R[5] = right;
}

__global__ __launch_bounds__(256, 8) void conv3x3_kernel(
    const float* __restrict__ X,
    const float* __restrict__ wt,
    float* __restrict__ out)
{
    const int y0   = blockIdx.x * ROWS;     // first output row of this block
    const int b    = blockIdx.y;            // batch
    const int c0   = threadIdx.x * 4;       // first of 4 output cols
    const int lane = threadIdx.x & 63;

    const float* img = X + (size_t)b * IMG_H * IMG_W;

    // uniform loads -> SGPRs
    const float w0 = wt[0], w1 = wt[1], w2 = wt[2];
    const float w3 = wt[3], w4 = wt[4], w5 = wt[5];
    const float w6 = wt[6], w7 = wt[7], w8 = wt[8];

    // rolling 3-row window; indices are compile-time constants after full
    // unroll (no dynamic indexing -> stays in registers)
    float R[3][6];
    load_row(img, y0 - 1, c0, lane, R[0]);
    load_row(img, y0,     c0, lane, R[1]);

    float* obase = out + ((size_t)b * IMG_H + y0) * IMG_W + c0;

#pragma unroll
    for (int i = 0; i < ROWS; ++i) {
        load_row(img, y0 + 1 + i, c0, lane, R[(i + 2) % 3]);
        const float (&ra)[6] = R[i % 3];
        const float (&rb)[6] = R[(i + 1) % 3];
        const float (&rc)[6] = R[(i + 2) % 3];
        vfloat4 r;
#pragma unroll
        for (int j = 0; j < 4; ++j) {
            r[j] = w0 * ra[j] + w1 * ra[j + 1] + w2 * ra[j + 2]
                 + w3 * rb[j] + w4 * rb[j + 1] + w5 * rb[j + 2]
                 + w6 * rc[j] + w7 * rc[j + 1] + w8 * rc[j + 2];
        }
        // nontemporal: write-once stream, keep L2 for input halo reuse
        __builtin_nontemporal_store(r, (vfloat4*)(obase + (size_t)i * IMG_W));
    }
}

extern "C" void kernel_launch(void* const* d_in, const int* in_sizes, int n_in,
                              void* d_out, int out_size, void* d_ws, size_t ws_size,
                              hipStream_t stream) {
    const float* X  = (const float*)d_in[0];
    const float* wt = (const float*)d_in[1];
    float* out = (float*)d_out;

    dim3 grid(IMG_H / ROWS, BATCH);   // 64 x 32 = 2048 blocks = 8 blocks/CU
    dim3 block(256);                  // 256 threads * 4 cols = 1024 cols
    conv3x3_kernel<<<grid, block, 0, stream>>>(X, wt, out);
}

// Round 3
// 232.989 us; speedup vs baseline: 1.0268x; 1.0268x over previous
//
#include <hip/hip_runtime.h>

#define IMG_W 1024
#define IMG_H 1024
#define BATCH 32
#define ROWS 8   // output rows per block; 10 input rows loaded upfront (deep MLP)

typedef float vfloat4 __attribute__((ext_vector_type(4)));

// Expand a loaded vfloat4 (cols c0..c0+3) into the 6-wide window c0-1..c0+4.
// Interior halo comes from neighbor lanes' registers via shuffle; the wave
// boundary lanes (0/63) substitute the pre-loaded halo value h.
__device__ __forceinline__ void expand(const vfloat4 v, float h, int lane,
                                       float (&R)[6])
{
    float left  = __shfl_up(v.w, 1);    // lane-1's col c0-1
    float right = __shfl_down(v.x, 1);  // lane+1's col c0+4
    if (lane == 0)  left  = h;          // wave boundary (or image edge -> 0)
    if (lane == 63) right = h;
    R[0] = left; R[1] = v.x; R[2] = v.y; R[3] = v.z; R[4] = v.w; R[5] = right;
}

__global__ __launch_bounds__(256, 6) void conv3x3_kernel(
    const float* __restrict__ X,
    const float* __restrict__ wt,
    float* __restrict__ out)
{
    const int y0   = blockIdx.x * ROWS;     // first output row of this block
    const int b    = blockIdx.y;            // batch
    const int c0   = threadIdx.x * 4;       // first of 4 output cols
    const int lane = threadIdx.x & 63;

    const float* img = X + (size_t)b * IMG_H * IMG_W;

    // uniform loads -> SGPRs
    const float w0 = wt[0], w1 = wt[1], w2 = wt[2];
    const float w3 = wt[3], w4 = wt[4], w5 = wt[5];
    const float w6 = wt[6], w7 = wt[7], w8 = wt[8];

    // ---- issue ALL input loads upfront: 10 dwordx4 + masked halo scalars ----
    // This is the MLP the rolling-window version lacked (it was latency-bound
    // at 31% HBM BW, VALUBusy 15%).
    vfloat4 V[ROWS + 2];
    float   H[ROWS + 2];   // lane 0 holds left halo, lane 63 holds right halo

#pragma unroll
    for (int i = 0; i < ROWS + 2; ++i) {
        const int ry = y0 + i - 1;
        float h = 0.f;
        if (ry >= 0 && ry < IMG_H) {
            const float* p = img + (size_t)ry * IMG_W + c0;
            V[i] = *(const vfloat4*)p;
            if (lane == 0  && c0 > 0)         h = p[-1];   // only thread 0 excluded
            if (lane == 63 && c0 + 4 < IMG_W) h = p[4];    // only thread 255 excluded
        } else {
            V[i] = (vfloat4){0.f, 0.f, 0.f, 0.f};
        }
        H[i] = h;
    }

    // ---- expand + compute with a rolling 3-row window (each row expanded once) ----
    float Rr[3][6];
    expand(V[0], H[0], lane, Rr[0]);
    expand(V[1], H[1], lane, Rr[1]);

    float* obase = out + ((size_t)b * IMG_H + y0) * IMG_W + c0;

#pragma unroll
    for (int i = 0; i < ROWS; ++i) {
        expand(V[i + 2], H[i + 2], lane, Rr[(i + 2) % 3]);  // static idx after unroll
        const float (&ra)[6] = Rr[i % 3];
        const float (&rb)[6] = Rr[(i + 1) % 3];
        const float (&rc)[6] = Rr[(i + 2) % 3];
        vfloat4 r;
#pragma unroll
        for (int j = 0; j < 4; ++j) {
            r[j] = w0 * ra[j] + w1 * ra[j + 1] + w2 * ra[j + 2]
                 + w3 * rb[j] + w4 * rb[j + 1] + w5 * rb[j + 2]
                 + w6 * rc[j] + w7 * rc[j + 1] + w8 * rc[j + 2];
        }
        // nontemporal: write-once stream, keep L2/L3 capacity for input reuse
        __builtin_nontemporal_store(r, (vfloat4*)(obase + (size_t)i * IMG_W));
    }
}

extern "C" void kernel_launch(void* const* d_in, const int* in_sizes, int n_in,
                              void* d_out, int out_size, void* d_ws, size_t ws_size,
                              hipStream_t stream) {
    const float* X  = (const float*)d_in[0];
    const float* wt = (const float*)d_in[1];
    float* out = (float*)d_out;

    dim3 grid(IMG_H / ROWS, BATCH);   // 128 x 32 = 4096 blocks
    dim3 block(256);                  // 256 threads * 4 cols = 1024 cols
    conv3x3_kernel<<<grid, block, 0, stream>>>(X, wt, out);
}

// Round 4
// 229.140 us; speedup vs baseline: 1.0441x; 1.0168x over previous
//
#include <hip/hip_runtime.h>

#define IMG_W 1024
#define IMG_H 1024
#define BATCH 32
#define ROWS 8   // output rows per thread

typedef float vfloat4 __attribute__((ext_vector_type(4)));

__global__ __launch_bounds__(256) void conv3x3_kernel(
    const float* __restrict__ X,
    const float* __restrict__ wt,
    float* __restrict__ out)
{
    const int y0 = blockIdx.x * ROWS;      // first output row of this block
    const int b  = blockIdx.y;             // batch
    const int c0 = threadIdx.x * 4;        // first of 4 output cols

    const float* img = X + (size_t)b * IMG_H * IMG_W;

    const float w0 = wt[0], w1 = wt[1], w2 = wt[2];
    const float w3 = wt[3], w4 = wt[4], w5 = wt[5];
    const float w6 = wt[6], w7 = wt[7], w8 = wt[8];

    // R[i] holds input row y0-1+i, cols c0-1 .. c0+4.
    // All 30 loads (10 dwordx4 + 20 scalar halo, all lanes) are issued in
    // this phase; the sched_barrier below forbids the compiler from sinking
    // them into the compute loop (round-3 post-mortem: VGPR=36 proved the
    // loads were being sunk, serializing memory round-trips per wave).
    float R[ROWS + 2][6];

#pragma unroll
    for (int i = 0; i < ROWS + 2; ++i) {
        const int ry = y0 + i - 1;
        if (ry >= 0 && ry < IMG_H) {
            const float* p = img + (size_t)ry * IMG_W + c0;
            const vfloat4 v = *(const vfloat4*)p;
            R[i][1] = v.x; R[i][2] = v.y; R[i][3] = v.z; R[i][4] = v.w;
            R[i][0] = (c0 > 0)         ? p[-1] : 0.f;   // L1-hit halo, adds MLP
            R[i][5] = (c0 + 4 < IMG_W) ? p[4]  : 0.f;
        } else {
            R[i][0] = R[i][1] = R[i][2] = R[i][3] = R[i][4] = R[i][5] = 0.f;
        }
    }

    // compile-time scheduling fence: nothing moves across — the 30 loads
    // above stay hoisted and live (forced deep MLP per wave)
    __builtin_amdgcn_sched_barrier(0);

    float* obase = out + ((size_t)b * IMG_H + y0) * IMG_W + c0;

#pragma unroll
    for (int i = 0; i < ROWS; ++i) {
        vfloat4 r;
#pragma unroll
        for (int j = 0; j < 4; ++j) {
            r[j] = w0 * R[i][j]     + w1 * R[i][j + 1]     + w2 * R[i][j + 2]
                 + w3 * R[i + 1][j] + w4 * R[i + 1][j + 1] + w5 * R[i + 1][j + 2]
                 + w6 * R[i + 2][j] + w7 * R[i + 2][j + 1] + w8 * R[i + 2][j + 2];
        }
        // nontemporal: don't let the write stream evict reusable input rows in L2
        __builtin_nontemporal_store(r, (vfloat4*)(obase + (size_t)i * IMG_W));
    }
}

extern "C" void kernel_launch(void* const* d_in, const int* in_sizes, int n_in,
                              void* d_out, int out_size, void* d_ws, size_t ws_size,
                              hipStream_t stream) {
    const float* X  = (const float*)d_in[0];
    const float* wt = (const float*)d_in[1];
    float* out = (float*)d_out;

    dim3 grid(IMG_H / ROWS, BATCH);   // 128 x 32 = 4096 blocks
    dim3 block(256);                  // 256 threads * 4 cols = 1024 cols
    conv3x3_kernel<<<grid, block, 0, stream>>>(X, wt, out);
}